// Round 9
// baseline (1463.463 us; speedup 1.0000x reference)
//
#include <hip/hip_runtime.h>

#define NTOK 49
#define CDIM 192
#define NHEAD 6
#define HDIM 32
#define VSTRIDE 401424  // 8192*49 + 16 pad (OOB-safe frag reads; garbage is P=0/bias-masked)

typedef float f32x4 __attribute__((ext_vector_type(4), may_alias));
typedef float f32x4u __attribute__((ext_vector_type(4), may_alias, aligned(4)));
typedef short b16x8 __attribute__((ext_vector_type(8), may_alias));
typedef short b16x4 __attribute__((ext_vector_type(4), may_alias));

__device__ __forceinline__ f32x4 MFMA(b16x8 a, b16x8 b, f32x4 c) {
  return __builtin_amdgcn_mfma_f32_16x16x32_bf16(a, b, c, 0, 0, 0);
}

__device__ __forceinline__ short f2bf(float f) {
  unsigned u = __builtin_bit_cast(unsigned, f);
  u += 0x7FFFu + ((u >> 16) & 1u);  // round-to-nearest-even
  return (short)(u >> 16);
}

// XOR swizzle for [64][192] bf16 tiles (granule 8 shorts = 16B), bijective/row.
__device__ __forceinline__ int swz(int r, int c) {
  return r * 192 + (c ^ ((r & 7) << 3));
}
// [16][32] P scratch: mix row bits 0-1 and 2-3.
__device__ __forceinline__ int ps(int r, int c) {
  return r * 32 + (c ^ ((((r & 3) ^ ((r >> 2) & 3)) & 3) << 3));
}

// ---- prep 1: fp32 weights -> bf16 ws. Wq pre-scaled by D^-0.5 ----
// ws shorts: [0,36864) Wq | [36864,110592) Wkv | [110592,147456) Wo
__global__ void prep_w(const float* __restrict__ Wq, const float* __restrict__ Wkv,
                       const float* __restrict__ Wo, short* __restrict__ wsW) {
  const float scale = 0.17677669529663687f;
  int i = blockIdx.x * 256 + threadIdx.x;
  if (i >= 147456) return;
  float v;
  if (i < 36864)        v = Wq[i] * scale;
  else if (i < 110592)  v = Wkv[i - 36864];
  else                  v = Wo[i - 110592];
  wsW[i] = f2bf(v);
}

// ---- prep 2: rel-pos-bias [6][49][64] f32; k-pad (49..63) = -1e9 mask ----
__global__ void prep_bias(const float* __restrict__ rpb, float* __restrict__ bias_t) {
  int idx = blockIdx.x * 256 + threadIdx.x;
  if (idx >= NHEAD * NTOK * 64) return;
  int k = idx & 63;
  int q = (idx >> 6) % NTOK;
  int h = idx / (NTOK * 64);
  float v = -1e9f;
  if (k < NTOK) {
    int ci = (q / 7) * 13 + (q % 7);
    int jj = 48 - k;
    int cj = (jj / 7) * 13 + (jj % 7);
    v = rpb[(ci + cj) * NHEAD + h];
  }
  bias_t[idx] = v;
}

// ================= K1: kv -> kh (flat row-major) + vT (flat chan-major), bf16 ====
// 256 thr (4 waves), 64 flat rows/block, A-frags in regs, 3 barriers.
__global__ __launch_bounds__(256, 4) void kproj_kernel(
    const float* __restrict__ kvg, const float* __restrict__ bkv,
    const short* __restrict__ wsW, short* __restrict__ khg,
    short* __restrict__ vtg) {
  __shared__ short KB[4][640];   // per-wave [16][40] K-write bounce
  __shared__ short VB[96 * 72];  // [96 chans][64 tok + 8 pad] transpose bounce

  const int blk = blockIdx.x;
  const int tid = threadIdx.x;
  const int w = tid >> 6;
  const int lane = tid & 63;
  const int l15 = lane & 15;
  const int lg = lane >> 4;
  const int r0 = blk * 64 + w * 16;
  const f32x4 zero4 = {0.f, 0.f, 0.f, 0.f};
  const short* WkvB = wsW + 36864;

  // A-fragments: 16 rows (r0+l15) x 192 k, f32 -> bf16, 24 VGPR
  b16x8 kvf[6];
#pragma unroll
  for (int kk = 0; kk < 6; ++kk) {
    const float* src = kvg + (size_t)(r0 + l15) * CDIM + kk * 32 + lg * 8;
    f32x4 lo = *(const f32x4*)(src);
    f32x4 hi = *(const f32x4*)(src + 4);
    b16x8 a = {f2bf(lo[0]), f2bf(lo[1]), f2bf(lo[2]), f2bf(lo[3]),
               f2bf(hi[0]), f2bf(hi[1]), f2bf(hi[2]), f2bf(hi[3])};
    kvf[kk] = a;
  }

  // ---- K half: 12 col-tiles, rolling acc, per-wave bounce (no block barrier) ----
#pragma unroll
  for (int ct = 0; ct < 12; ++ct) {
    const int col = ct * 16 + l15;
    f32x4 acc = zero4;
#pragma unroll
    for (int kk = 0; kk < 6; ++kk) {
      b16x8 bw = *(const b16x8*)(WkvB + col * CDIM + kk * 32 + lg * 8);
      acc = MFMA(kvf[kk], bw, acc);
    }
    const float bias = bkv[col];
#pragma unroll
    for (int rr = 0; rr < 4; ++rr)
      KB[w][(lg * 4 + rr) * 40 + (ct & 1) * 16 + l15] = f2bf(acc[rr] + bias);
    if (ct & 1) {  // flush 16 rows x 32 cols (same-wave LDS RAW is ordered)
      const int row = lane >> 2, seg = lane & 3;
      b16x8 v = *(const b16x8*)(&KB[w][row * 40 + seg * 8]);
      *(b16x8*)(khg + (size_t)(r0 + row) * CDIM + (ct - 1) * 16 + seg * 8) = v;
    }
  }

  // ---- V half: 2 groups of 96 chans; LDS transpose -> coalesced vT writes ----
#pragma unroll
  for (int g = 0; g < 2; ++g) {
#pragma unroll
    for (int tt = 0; tt < 6; ++tt) {
      const int col = CDIM + g * 96 + tt * 16 + l15;
      f32x4 acc = zero4;
#pragma unroll
      for (int kk = 0; kk < 6; ++kk) {
        b16x8 bw = *(const b16x8*)(WkvB + col * CDIM + kk * 32 + lg * 8);
        acc = MFMA(kvf[kk], bw, acc);
      }
      const float bias = bkv[col];
      b16x4 o = {f2bf(acc[0] + bias), f2bf(acc[1] + bias),
                 f2bf(acc[2] + bias), f2bf(acc[3] + bias)};
      // VB[chan-in-group][token]; tokens w*16+lg*4..+3 (wave-disjoint)
      *(b16x4*)(&VB[(tt * 16 + l15) * 72 + w * 16 + lg * 4]) = o;
    }
    __syncthreads();  // VB complete
    for (int u = tid; u < 384; u += 256) {  // 96 chans x 4 16-tok segs
      const int c = u >> 2, s = u & 2 ? (u & 3) : (u & 3);  // s = u & 3
      b16x8 a = *(const b16x8*)(&VB[c * 72 + (u & 3) * 16]);
      b16x8 b2 = *(const b16x8*)(&VB[c * 72 + (u & 3) * 16 + 8]);
      short* dst = vtg + (size_t)(g * 96 + c) * VSTRIDE + blk * 64 + (u & 3) * 16;
      *(b16x8*)(dst) = a;
      *(b16x8*)(dst + 8) = b2;
      (void)s;
    }
    __syncthreads();  // VB reusable
  }
}

// ================= K2: q + kh/vT -> attention + o-proj -> out =================
// 1 window/block, 8 waves. Pair loop is BARRIER-FREE: bk/bv direct from global
// (16B-contiguous frags), P bounce per-wave. LDS 32768 B.
__global__ __launch_bounds__(512, 4) void attn_kernel(
    const float* __restrict__ qg, const float* __restrict__ maskg,
    const float* __restrict__ bq, const float* __restrict__ bo,
    const short* __restrict__ wsW, const float* __restrict__ bias_t,
    const short* __restrict__ khg, const short* __restrict__ vtg,
    float* __restrict__ outg, int nW) {
  __shared__ short lds[16384];  // 32768 B: X [0,12288) | PS [12288,16384)
  short* X = lds;               // [64][192] swizzled: qh scratch -> x
  short* PS = lds + 12288;      // per-wave [16][32] P scratch
  float* BF = (float*)lds;      // epilogue bounce [32][196] f32 (25088 B)

  const int b = blockIdx.x;
  const int tid = threadIdx.x;
  const int w = tid >> 6;
  const int lane = tid & 63;
  const int l15 = lane & 15;
  const int lg = lane >> 4;
  const int R = w >> 1, hw = w & 1;
  const f32x4 zero4 = {0.f, 0.f, 0.f, 0.f};

  const short* WqB = wsW;
  const short* WoB = wsW + 110592;

  const float* qsrc = qg + (size_t)b * (NTOK * CDIM);
  const float* maskw = maskg + (size_t)(b % nW) * (NTOK * NTOK);
  const short* khb = khg + (size_t)b * 49 * CDIM;

  const int qrow = R * 16 + l15;
  const int qc = qrow > 48 ? 48 : qrow;

  // ---- q-projection (per-wave; R8-verified) ----
  b16x8 aq6[6];
#pragma unroll
  for (int kk = 0; kk < 6; ++kk) {
    f32x4 lo = *(const f32x4*)(qsrc + qc * CDIM + kk * 32 + lg * 8);
    f32x4 hi = *(const f32x4*)(qsrc + qc * CDIM + kk * 32 + lg * 8 + 4);
    b16x8 a = {f2bf(lo[0]), f2bf(lo[1]), f2bf(lo[2]), f2bf(lo[3]),
               f2bf(hi[0]), f2bf(hi[1]), f2bf(hi[2]), f2bf(hi[3])};
    aq6[kk] = a;
  }
#pragma unroll
  for (int t = 0; t < 6; ++t) {
    const int col = (2 * (t >> 1) + hw) * 32 + (t & 1) * 16 + l15;
    f32x4 acc = zero4;
#pragma unroll
    for (int kk = 0; kk < 6; ++kk) {
      b16x8 bw = *(const b16x8*)(WqB + col * CDIM + kk * 32 + lg * 8);
      acc = MFMA(aq6[kk], bw, acc);
    }
    const float bias = bq[col] * 0.17677669529663687f;
#pragma unroll
    for (int rr = 0; rr < 4; ++rr)
      X[swz(R * 16 + lg * 4 + rr, hw * 96 + t * 16 + l15)] = f2bf(acc[rr] + bias);
  }
  b16x8 aq[3];
#pragma unroll
  for (int p = 0; p < 3; ++p)
    aq[p] = *(const b16x8*)(X + swz(R * 16 + l15, hw * 96 + p * 32 + lg * 8));
  __syncthreads();  // B1: all qh reads done; X free for x

  // ---- pair loop: ZERO barriers ----
  b16x8 xbf[3];
#pragma unroll
  for (int p = 0; p < 3; ++p) {
    const int h = 2 * p + hw;
    f32x4 Ls[4];
#pragma unroll
    for (int nt = 0; nt < 4; ++nt) {
      b16x8 bk = *(const b16x8*)(khb + (size_t)(nt * 16 + l15) * CDIM +
                                 h * HDIM + lg * 8);
      Ls[nt] = MFMA(bk, aq[p], zero4);
    }
    const float* bt = bias_t + (h * NTOK + qc) * 64;
#pragma unroll
    for (int nt = 0; nt < 4; ++nt) {
      f32x4 bb = *(const f32x4*)(bt + nt * 16 + lg * 4);
#pragma unroll
      for (int rr = 0; rr < 4; ++rr) Ls[nt][rr] += bb[rr];
    }
#pragma unroll
    for (int nt = 0; nt < 3; ++nt) {
      f32x4 mm = *(const f32x4u*)(maskw + qc * NTOK + nt * 16 + lg * 4);
#pragma unroll
      for (int rr = 0; rr < 4; ++rr) Ls[nt][rr] += mm[rr];
    }
    if (lg == 0) Ls[3][0] += maskw[qc * NTOK + 48];

    float mx = Ls[0][0];
#pragma unroll
    for (int nt = 0; nt < 4; ++nt)
#pragma unroll
      for (int rr = 0; rr < 4; ++rr) mx = fmaxf(mx, Ls[nt][rr]);
    mx = fmaxf(mx, __shfl_xor(mx, 16));
    mx = fmaxf(mx, __shfl_xor(mx, 32));
    float sum = 0.f;
#pragma unroll
    for (int nt = 0; nt < 4; ++nt)
#pragma unroll
      for (int rr = 0; rr < 4; ++rr) {
        Ls[nt][rr] = __expf(Ls[nt][rr] - mx);
        sum += Ls[nt][rr];
      }
    sum += __shfl_xor(sum, 16);
    sum += __shfl_xor(sum, 32);
    const float inv = 1.f / sum;

    short* Pscr = PS + w * 512;  // per-wave: no barrier
    b16x8 ap[2];
#pragma unroll
    for (int kkh = 0; kkh < 2; ++kkh) {
#pragma unroll
      for (int nth = 0; nth < 2; ++nth) {
        const int nt = 2 * kkh + nth;
        b16x4 o = {f2bf(Ls[nt][0] * inv), f2bf(Ls[nt][1] * inv),
                   f2bf(Ls[nt][2] * inv), f2bf(Ls[nt][3] * inv)};
        *(b16x4*)(Pscr + ps(l15, nth * 16 + lg * 4)) = o;
      }
      ap[kkh] = *(const b16x8*)(Pscr + ps(l15, lg * 8));
    }
    f32x4 xa[2] = {zero4, zero4};
#pragma unroll
    for (int kkh = 0; kkh < 2; ++kkh)
#pragma unroll
      for (int nv = 0; nv < 2; ++nv) {
        b16x8 bv = *(const b16x8*)(vtg + (size_t)(h * HDIM + nv * 16 + l15) * VSTRIDE +
                                   b * 49 + kkh * 32 + lg * 8);
        xa[nv] = MFMA(ap[kkh], bv, xa[nv]);
      }
    b16x8 xb = {f2bf(xa[0][0]), f2bf(xa[0][1]), f2bf(xa[0][2]), f2bf(xa[0][3]),
                f2bf(xa[1][0]), f2bf(xa[1][1]), f2bf(xa[1][2]), f2bf(xa[1][3])};
    xbf[p] = xb;
  }

  // ---- x -> X ----
#pragma unroll
  for (int p = 0; p < 3; ++p) {
    const int h = 2 * p + hw;
#pragma unroll
    for (int nv = 0; nv < 2; ++nv)
#pragma unroll
      for (int rr = 0; rr < 4; ++rr)
        X[swz(R * 16 + lg * 4 + rr, h * HDIM + nv * 16 + l15)] = xbf[p][nv * 4 + rr];
  }
  __syncthreads();  // B2: x complete

  // ---- output projection ----
  f32x4 oacc[6];
#pragma unroll
  for (int t = 0; t < 6; ++t) oacc[t] = zero4;
#pragma unroll
  for (int t = 0; t < 6; ++t) {
    const int j = 2 * t + (w >> 2);
    const int m = w & 3;
    const int col = j * 16 + l15;
#pragma unroll
    for (int kk = 0; kk < 6; ++kk) {
      b16x8 a = *(const b16x8*)(X + swz(m * 16 + l15, kk * 32 + lg * 8));
      b16x8 bw = *(const b16x8*)(WoB + col * CDIM + kk * 32 + lg * 8);
      oacc[t] = MFMA(a, bw, oacc[t]);
    }
  }
  __syncthreads();  // B3: X reads done -> lds = f32 bounce [32][196]

  float* dst = outg + (size_t)b * (NTOK * CDIM);
  if ((w & 3) < 2) {
#pragma unroll
    for (int t = 0; t < 6; ++t) {
      const int col = (2 * t + (w >> 2)) * 16 + l15;
      const float bias = bo[col];
#pragma unroll
      for (int rr = 0; rr < 4; ++rr)
        BF[((w & 3) * 16 + lg * 4 + rr) * 196 + col] = oacc[t][rr] + bias;
    }
  }
  __syncthreads();
#pragma unroll
  for (int it = 0; it < 3; ++it) {
    int idx = tid + it * 512;
    int row = idx / 48, c4 = idx % 48;
    *(f32x4*)(dst + row * CDIM + c4 * 4) = *(const f32x4*)(BF + row * 196 + c4 * 4);
  }
  __syncthreads();
  if ((w & 3) >= 2) {
#pragma unroll
    for (int t = 0; t < 6; ++t) {
      const int col = (2 * t + (w >> 2)) * 16 + l15;
      const float bias = bo[col];
#pragma unroll
      for (int rr = 0; rr < 4; ++rr)
        BF[(((w & 3) - 2) * 16 + lg * 4 + rr) * 196 + col] = oacc[t][rr] + bias;
    }
  }
  __syncthreads();
#pragma unroll
  for (int it = 0; it < 2; ++it) {
    int idx = tid + it * 512;
    if (idx < 17 * 48) {
      int row2 = idx / 48, c4 = idx % 48;
      *(f32x4*)(dst + (32 + row2) * CDIM + c4 * 4) =
          *(const f32x4*)(BF + row2 * 196 + c4 * 4);
    }
  }
}

extern "C" void kernel_launch(void* const* d_in, const int* in_sizes, int n_in,
                              void* d_out, int out_size, void* d_ws, size_t ws_size,
                              hipStream_t stream) {
  const float* q = (const float*)d_in[0];
  const float* kv = (const float*)d_in[1];
  const float* mask = (const float*)d_in[2];
  const float* Wq = (const float*)d_in[3];
  const float* bq = (const float*)d_in[4];
  const float* Wkv = (const float*)d_in[5];
  const float* bkv = (const float*)d_in[6];
  const float* Wo = (const float*)d_in[7];
  const float* bo = (const float*)d_in[8];
  const float* rpb = (const float*)d_in[9];

  // ws layout (bytes): [0,294912) weights bf16 | [294912,370176) bias_t f32
  //                    | [370176, +154146816) kh | then vT (154146816)
  short* wsW = (short*)d_ws;
  float* bias_t = (float*)((char*)d_ws + 294912);
  short* khg = (short*)((char*)d_ws + 370176);
  short* vtg = khg + (size_t)VSTRIDE * CDIM;

  const int B = in_sizes[0] / (NTOK * CDIM);     // 8192
  const int nW = in_sizes[2] / (NTOK * NTOK);    // 64
  const int nrows = B * NTOK;                    // 401408

  prep_w<<<576, 256, 0, stream>>>(Wq, Wkv, Wo, wsW);
  prep_bias<<<(NHEAD * NTOK * 64 + 255) / 256, 256, 0, stream>>>(rpb, bias_t);
  kproj_kernel<<<nrows / 64, 256, 0, stream>>>(kv, bkv, wsW, khg, vtg);
  attn_kernel<<<B, 512, 0, stream>>>(q, mask, bq, bo, wsW, bias_t, khg, vtg,
                                     (float*)d_out, nW);
}

// Round 10
// 1243.064 us; speedup vs baseline: 1.1773x; 1.1773x over previous
//
#include <hip/hip_runtime.h>

#define NTOK 49
#define CDIM 192
#define NHEAD 6
#define HDIM 32

typedef float f32x4 __attribute__((ext_vector_type(4), may_alias));
typedef float f32x4u __attribute__((ext_vector_type(4), may_alias, aligned(4)));
typedef short b16x8 __attribute__((ext_vector_type(8), may_alias));
typedef short b16x4 __attribute__((ext_vector_type(4), may_alias));

__device__ __forceinline__ f32x4 MFMA(b16x8 a, b16x8 b, f32x4 c) {
  return __builtin_amdgcn_mfma_f32_16x16x32_bf16(a, b, c, 0, 0, 0);
}

// Native cast -> v_cvt_pk_bf16_f32 (RNE); compiler fuses pairs (m240: prefer
// compiler casts over hand-written cvt asm and over manual bit-twiddle).
__device__ __forceinline__ short f2bf(float f) {
  __bf16 h = (__bf16)f;
  return __builtin_bit_cast(short, h);
}

// XOR swizzles (granule 8 shorts = 16B), bijective per row. All verified R5-R9.
__device__ __forceinline__ int swz(int r, int c) {   // [64][192]
  return r * 192 + (c ^ ((r & 7) << 3));
}
__device__ __forceinline__ int swz64(int r, int c) { // [192][64] (row=chan)
  return r * 64 + (c ^ ((r & 7) << 3));
}
__device__ __forceinline__ int ps(int r, int c) {    // [16][32] P scratch
  return r * 32 + (c ^ ((((r & 3) ^ ((r >> 2) & 3)) & 3) << 3));
}

// ---- prep 1: fp32 weights -> bf16 ws. Wq pre-scaled by D^-0.5 ----
__global__ void prep_w(const float* __restrict__ Wq, const float* __restrict__ Wkv,
                       const float* __restrict__ Wo, short* __restrict__ wsW) {
  const float scale = 0.17677669529663687f;
  int i = blockIdx.x * 256 + threadIdx.x;
  if (i >= 147456) return;
  float v;
  if (i < 36864)        v = Wq[i] * scale;
  else if (i < 110592)  v = Wkv[i - 36864];
  else                  v = Wo[i - 110592];
  wsW[i] = f2bf(v);
}

// ---- prep 2: rel-pos-bias [6][49][64] f32; k-pad (49..63) = -1e9 mask ----
__global__ void prep_bias(const float* __restrict__ rpb, float* __restrict__ bias_t) {
  int idx = blockIdx.x * 256 + threadIdx.x;
  if (idx >= NHEAD * NTOK * 64) return;
  int k = idx & 63;
  int q = (idx >> 6) % NTOK;
  int h = idx / (NTOK * 64);
  float v = -1e9f;
  if (k < NTOK) {
    int ci = (q / 7) * 13 + (q % 7);
    int jj = 48 - k;
    int cj = (jj / 7) * 13 + (jj % 7);
    v = rpb[(ci + cj) * NHEAD + h];
  }
  bias_t[idx] = v;
}

// Fused window-MSA, minimal-barrier edition: 1 window/block, 8 waves, 7 barriers.
// LDS (shorts): X [0,12288) | KH [12288,24576) | VT [24576,36864)  (73728 B).
// Residency is wave-capped (~16 waves/CU at VGPR~64), NOT LDS-capped, so the
// bigger KH/VT (full kv-proj in one parallel phase) costs nothing.
// X: per-wave qh scratch -> kv stage -> per-wave P scratch -> x.
// Swapped QK^T (lane owns q-row, in-lane softmax, 2 shuffles). Epilogue: f32
// bounce overlaid on KH+VT, single pass, coalesced stores.
__global__ __launch_bounds__(512, 4) void wmsa_kernel(
    const float* __restrict__ qg, const float* __restrict__ kvg,
    const float* __restrict__ maskg, const float* __restrict__ bq,
    const float* __restrict__ bkv, const float* __restrict__ bo,
    const short* __restrict__ wsW, const float* __restrict__ bias_t,
    float* __restrict__ outg, int nW) {
  __shared__ short lds[36864];      // 73728 B
  short* X = lds;
  short* KH = lds + 12288;
  short* VT = lds + 24576;
  float* BF = (float*)(lds + 12288);  // epilogue [49][196] f32 = 38416 B <= 49152

  const int b = blockIdx.x;
  const int tid = threadIdx.x;
  const int w = tid >> 6;
  const int lane = tid & 63;
  const int l15 = lane & 15;
  const int lg = lane >> 4;
  const int R = w >> 1, hw = w & 1;
  const f32x4 zero4 = {0.f, 0.f, 0.f, 0.f};

  const short* WqB = wsW;
  const short* WkvB = wsW + 36864;
  const short* WoB = wsW + 110592;

  const float* qsrc = qg + (size_t)b * (NTOK * CDIM);
  const float* kvsrc = kvg + (size_t)b * (NTOK * CDIM);
  const float* maskw = maskg + (size_t)(b % nW) * (NTOK * NTOK);

  const int qrow = R * 16 + l15;
  const int qc = qrow > 48 ? 48 : qrow;  // pad lanes -> row 48 (outputs unused)

  // ============ 1. q-projection (per-wave; verified R8/R9) ============
  b16x8 aq6[6];
#pragma unroll
  for (int kk = 0; kk < 6; ++kk) {
    f32x4 lo = *(const f32x4*)(qsrc + qc * CDIM + kk * 32 + lg * 8);
    f32x4 hi = *(const f32x4*)(qsrc + qc * CDIM + kk * 32 + lg * 8 + 4);
    b16x8 a = {f2bf(lo[0]), f2bf(lo[1]), f2bf(lo[2]), f2bf(lo[3]),
               f2bf(hi[0]), f2bf(hi[1]), f2bf(hi[2]), f2bf(hi[3])};
    aq6[kk] = a;
  }
#pragma unroll
  for (int t = 0; t < 6; ++t) {
    const int col = (2 * (t >> 1) + hw) * 32 + (t & 1) * 16 + l15;
    f32x4 acc = zero4;
#pragma unroll
    for (int kk = 0; kk < 6; ++kk) {
      b16x8 bw = *(const b16x8*)(WqB + col * CDIM + kk * 32 + lg * 8);
      acc = MFMA(aq6[kk], bw, acc);
    }
    const float bias = bq[col] * 0.17677669529663687f;
#pragma unroll
    for (int rr = 0; rr < 4; ++rr)
      X[swz(R * 16 + lg * 4 + rr, hw * 96 + t * 16 + l15)] = f2bf(acc[rr] + bias);
  }
  b16x8 aq[3];
#pragma unroll
  for (int p = 0; p < 3; ++p)
    aq[p] = *(const b16x8*)(X + swz(R * 16 + l15, hw * 96 + p * 32 + lg * 8));
  __syncthreads();  // B1

  // ============ 2. stage kv -> X (bf16, rows>=49 zero) ============
#pragma unroll
  for (int it = 0; it < 6; ++it) {
    int idx = tid + it * 512;
    int r = idx / 48, c4 = idx % 48;
    f32x4 v = (r < NTOK) ? *(const f32x4*)(kvsrc + r * CDIM + c4 * 4) : zero4;
    b16x4 o = {f2bf(v[0]), f2bf(v[1]), f2bf(v[2]), f2bf(v[3])};
    *(b16x4*)(X + swz(r, c4 * 4)) = o;
  }
  __syncthreads();  // B2

  // ============ 3. kv-projection, one parallel phase (verified R5) ============
  // wave w -> col-tiles w*3+{0,1,2} of 24 (cols 0..383)
#pragma unroll
  for (int jj = 0; jj < 3; ++jj) {
    const int nt = w * 3 + jj;
    const int col = nt * 16 + l15;
    f32x4 acc[4];
#pragma unroll
    for (int m = 0; m < 4; ++m) acc[m] = zero4;
#pragma unroll
    for (int kk = 0; kk < 6; ++kk) {
      b16x8 bw = *(const b16x8*)(WkvB + col * CDIM + kk * 32 + lg * 8);
#pragma unroll
      for (int m = 0; m < 4; ++m) {
        b16x8 a = *(const b16x8*)(X + swz(m * 16 + l15, kk * 32 + lg * 8));
        acc[m] = MFMA(a, bw, acc[m]);
      }
    }
    const float bias = bkv[col];
    if (col < CDIM) {  // K -> KH[token][chan]
#pragma unroll
      for (int m = 0; m < 4; ++m)
#pragma unroll
        for (int rr = 0; rr < 4; ++rr)
          KH[swz(m * 16 + lg * 4 + rr, col)] = f2bf(acc[m][rr] + bias);
    } else {  // V -> VT[chan][token]
      const int c = col - CDIM;
#pragma unroll
      for (int m = 0; m < 4; ++m) {
        b16x4 o = {f2bf(acc[m][0] + bias), f2bf(acc[m][1] + bias),
                   f2bf(acc[m][2] + bias), f2bf(acc[m][3] + bias)};
        *(b16x4*)(VT + swz64(c, m * 16 + lg * 4)) = o;
      }
    }
  }
  __syncthreads();  // B3: kh/vT ready; X(kv) dead -> P scratch

  // ============ 4. pair loop: ZERO barriers (verified R8 mechanics) ============
  b16x8 xbf[3];
#pragma unroll
  for (int p = 0; p < 3; ++p) {
    const int h = 2 * p + hw;
    f32x4 Ls[4];
#pragma unroll
    for (int nt = 0; nt < 4; ++nt) {
      b16x8 bk = *(const b16x8*)(KH + swz(nt * 16 + l15, h * HDIM + lg * 8));
      Ls[nt] = MFMA(bk, aq[p], zero4);
    }
    const float* bt = bias_t + (h * NTOK + qc) * 64;
#pragma unroll
    for (int nt = 0; nt < 4; ++nt) {
      f32x4 bb = *(const f32x4*)(bt + nt * 16 + lg * 4);
#pragma unroll
      for (int rr = 0; rr < 4; ++rr) Ls[nt][rr] += bb[rr];
    }
#pragma unroll
    for (int nt = 0; nt < 3; ++nt) {
      f32x4 mm = *(const f32x4u*)(maskw + qc * NTOK + nt * 16 + lg * 4);
#pragma unroll
      for (int rr = 0; rr < 4; ++rr) Ls[nt][rr] += mm[rr];
    }
    if (lg == 0) Ls[3][0] += maskw[qc * NTOK + 48];

    float mx = Ls[0][0];
#pragma unroll
    for (int nt = 0; nt < 4; ++nt)
#pragma unroll
      for (int rr = 0; rr < 4; ++rr) mx = fmaxf(mx, Ls[nt][rr]);
    mx = fmaxf(mx, __shfl_xor(mx, 16));
    mx = fmaxf(mx, __shfl_xor(mx, 32));
    float sum = 0.f;
#pragma unroll
    for (int nt = 0; nt < 4; ++nt)
#pragma unroll
      for (int rr = 0; rr < 4; ++rr) {
        Ls[nt][rr] = __expf(Ls[nt][rr] - mx);
        sum += Ls[nt][rr];
      }
    sum += __shfl_xor(sum, 16);
    sum += __shfl_xor(sum, 32);
    const float inv = 1.f / sum;

    short* Pscr = X + w * 512;  // per-wave [16][32] in dead kv region
    b16x8 ap[2];
#pragma unroll
    for (int kkh = 0; kkh < 2; ++kkh) {
#pragma unroll
      for (int nth = 0; nth < 2; ++nth) {
        const int nt = 2 * kkh + nth;
        b16x4 o = {f2bf(Ls[nt][0] * inv), f2bf(Ls[nt][1] * inv),
                   f2bf(Ls[nt][2] * inv), f2bf(Ls[nt][3] * inv)};
        *(b16x4*)(Pscr + ps(l15, nth * 16 + lg * 4)) = o;
      }
      ap[kkh] = *(const b16x8*)(Pscr + ps(l15, lg * 8));
    }
    f32x4 xa[2] = {zero4, zero4};
#pragma unroll
    for (int kkh = 0; kkh < 2; ++kkh)
#pragma unroll
      for (int nv = 0; nv < 2; ++nv) {
        b16x8 bv = *(const b16x8*)(VT + swz64(h * HDIM + nv * 16 + l15,
                                              kkh * 32 + lg * 8));
        xa[nv] = MFMA(ap[kkh], bv, xa[nv]);
      }
    b16x8 xb = {f2bf(xa[0][0]), f2bf(xa[0][1]), f2bf(xa[0][2]), f2bf(xa[0][3]),
                f2bf(xa[1][0]), f2bf(xa[1][1]), f2bf(xa[1][2]), f2bf(xa[1][3])};
    xbf[p] = xb;
  }
  __syncthreads();  // B4: all P-scratch reads done -> X writable as x

  // ============ 5. x -> X (rows 0..63 all covered; 49+ = finite dup of row 48) ====
#pragma unroll
  for (int p = 0; p < 3; ++p) {
    const int h = 2 * p + hw;
#pragma unroll
    for (int nv = 0; nv < 2; ++nv)
#pragma unroll
      for (int rr = 0; rr < 4; ++rr)
        X[swz(R * 16 + lg * 4 + rr, h * HDIM + nv * 16 + l15)] = xbf[p][nv * 4 + rr];
  }
  __syncthreads();  // B5: x ready

  // ============ 6. output projection ============
  f32x4 oacc[6];
#pragma unroll
  for (int t = 0; t < 6; ++t) oacc[t] = zero4;
#pragma unroll
  for (int t = 0; t < 6; ++t) {
    const int j = 2 * t + (w >> 2);
    const int m = w & 3;
    const int col = j * 16 + l15;
#pragma unroll
    for (int kk = 0; kk < 6; ++kk) {
      b16x8 a = *(const b16x8*)(X + swz(m * 16 + l15, kk * 32 + lg * 8));
      b16x8 bw = *(const b16x8*)(WoB + col * CDIM + kk * 32 + lg * 8);
      oacc[t] = MFMA(a, bw, oacc[t]);
    }
  }
  __syncthreads();  // B6: KH/VT dead -> BF overlay writable

  // ---- single-pass f32 bounce [49][196] in KH+VT region ----
  {
    const int m = w & 3;
#pragma unroll
    for (int t = 0; t < 6; ++t) {
      const int col = (2 * t + (w >> 2)) * 16 + l15;
      const float bias = bo[col];
#pragma unroll
      for (int rr = 0; rr < 4; ++rr) {
        const int row = m * 16 + lg * 4 + rr;
        if (row < NTOK) BF[row * 196 + col] = oacc[t][rr] + bias;
      }
    }
  }
  __syncthreads();  // B7

  float* dst = outg + (size_t)b * (NTOK * CDIM);
#pragma unroll
  for (int it = 0; it < 5; ++it) {
    int idx = tid + it * 512;
    if (idx < NTOK * 48) {
      int row = idx / 48, c4 = idx % 48;
      *(f32x4*)(dst + row * CDIM + c4 * 4) = *(const f32x4*)(BF + row * 196 + c4 * 4);
    }
  }
}

extern "C" void kernel_launch(void* const* d_in, const int* in_sizes, int n_in,
                              void* d_out, int out_size, void* d_ws, size_t ws_size,
                              hipStream_t stream) {
  const float* q = (const float*)d_in[0];
  const float* kv = (const float*)d_in[1];
  const float* mask = (const float*)d_in[2];
  const float* Wq = (const float*)d_in[3];
  const float* bq = (const float*)d_in[4];
  const float* Wkv = (const float*)d_in[5];
  const float* bkv = (const float*)d_in[6];
  const float* Wo = (const float*)d_in[7];
  const float* bo = (const float*)d_in[8];
  const float* rpb = (const float*)d_in[9];
  short* wsW = (short*)d_ws;
  float* bias_t = (float*)((char*)d_ws + 294912);  // [6][49][64] f32, 75264 B

  const int B = in_sizes[0] / (NTOK * CDIM);
  const int nW = in_sizes[2] / (NTOK * NTOK);

  prep_w<<<576, 256, 0, stream>>>(Wq, Wkv, Wo, wsW);
  prep_bias<<<(NHEAD * NTOK * 64 + 255) / 256, 256, 0, stream>>>(rpb, bias_t);
  wmsa_kernel<<<B, 512, 0, stream>>>(q, kv, mask, bq, bkv, bo, wsW, bias_t,
                                     (float*)d_out, nW);
}